// Round 6
// baseline (136.504 us; speedup 1.0000x reference)
//
#include <hip/hip_runtime.h>
#include <hip/hip_bf16.h>
#include <math.h>

#define SUMS 199
#define NBLK 1024   // 16 images = 4 batch elements per block, 256 threads

typedef __attribute__((ext_vector_type(8))) short short8;   // 8 bf16
typedef __attribute__((ext_vector_type(4))) float float4v;  // MFMA acc

union Frag8 { short8 v; unsigned u[4]; uint4 q; };

static __device__ inline unsigned pk_bf16(float a, float b) {
    __hip_bfloat162 h = __float22bfloat162_rn(make_float2(a, b));
    union { __hip_bfloat162 h; unsigned u; } c; c.h = h; return c.u;
}

// ---- pre-kernel: all weight fragments -> d_ws (bf16 frag layout) ----
// c2 K-map (dense): pos = 4*s + h, ky = pos/5, kx = pos%5, valid pos < 25
// => conv2 needs only 7 K-steps (K=224) instead of 8 (K=256).
__global__ __launch_bounds__(256) void convert_weights(
    const float* __restrict__ f1w, const float* __restrict__ f2w,
    const float* __restrict__ f3w, const float* __restrict__ c1w,
    const float* __restrict__ c2w, uint4* __restrict__ ws)
{
    const int g = blockIdx.x * 256 + threadIdx.x;
    if (g >= 6400) return;
    float v[8];
    if (g < 5824) {
        const float* W; int O, K, ld, nt, s, l;
        if (g < 4096)      { W = f1w; O = 120; K = 256; ld = 256; nt = g >> 9; s = (g >> 6) & 7; l = g & 63; }
        else if (g < 5632) { const int f = g - 4096; W = f2w; O = 84; K = 120; ld = 120; nt = f >> 8; s = (f >> 6) & 3; l = f & 63; }
        else               { const int f = g - 5632; W = f3w; O = 10; K = 84;  ld = 84;  nt = 0; s = f >> 6; l = f & 63; }
        const int o = nt * 16 + (l & 15);
        #pragma unroll
        for (int j = 0; j < 8; ++j) {
            const int k = 32 * s + 8 * (l >> 4) + j;
            v[j] = (o < O && k < K) ? W[o * ld + k] : 0.f;
        }
    } else if (g < 6336) {
        const int f = g - 5824, s = f >> 6, l = f & 63;
        const int c = l & 15, h = l >> 4;
        const int pos = 4 * s + h;           // dense position index
        const int ky = pos / 5, kx = pos % 5;
        const bool ok = (pos < 25);
        #pragma unroll
        for (int jp = 0; jp < 4; ++jp) {
            v[2 * jp]     = (ok && 2 * jp < 6)     ? c2w[c * 150 + (2 * jp) * 25 + ky * 5 + kx]     : 0.f;
            v[2 * jp + 1] = (ok && 2 * jp + 1 < 6) ? c2w[c * 150 + (2 * jp + 1) * 25 + ky * 5 + kx] : 0.f;
        }
    } else {
        const int l = (g - 6336) & 63;
        const int c = l & 15, h = l >> 4;
        const int oc = c >> 1, xs = c & 1;
        #pragma unroll
        for (int j = 0; j < 8; ++j) {
            const int p = h * 4 + (j >> 1);
            float w = 0.f;
            if (p < 15 && c < 12) {
                const int ky = p / 3, kx = 2 * (p % 3) + (j & 1) - xs;
                if (kx >= 0 && kx < 5) w = c1w[oc * 25 + ky * 5 + kx];
            }
            v[j] = w;
        }
    }
    uint4 r;
    r.x = pk_bf16(v[0], v[1]); r.y = pk_bf16(v[2], v[3]);
    r.z = pk_bf16(v[4], v[5]); r.w = pk_bf16(v[6], v[7]);
    ws[g] = r;
}

// LDS map (39680 B, 4 blocks/CU):
//  [0,12672)      imgu bf16 [8 img][396 dw] per pass. After convs: A2
//                 [16][68dw]@0, A3 [16][52dw]@4352, pgf [16][12]f32 @7680,
//                 Hf/Lf [4][20]f32 @8448/@8768.
//  [12672,31232)  p1 bf16 [8 img][145 uint4], ch-6/7 dwords stay zero.
//  [31232,39680)  A1 bf16 [16 img][132 dw]
//
// Wave-private front (R3, best measured): wave w owns images {2w,2w+1} of
// each pass end-to-end (stage -> conv1 with N-cols (irel,parity,qxo) ->
// conv2); all hazards are same-wave DS program order; barriers only at
// A1->fc1, fc1->fc2, fc2->tail.
//
// R6: fc B-fragment prefetch. fc1/fc2/fc3 read their MFMA B-operands from
// global (wsb, L2-hot). Previously issued inside acc-dependent loops =>
// serialized L2 waits. Now: fc1 s=0..3 issued BEFORE the A1 barrier
// (latency hides under the drain), s=4..7 as one batch inside fc1; fc2's 8
// frags before the fc1 barrier; fc3's 3 before the fc2 barrier.
//
// Circuit factorization (exact regroup): n1+n2 = 10(h1+h2)+(l1+l2) =>
// P_sum = (ptens1 (*) ptens2) outer-convolved with (pones1 (*) pones2);
// H,L are 19-long convs; each of the 199 outputs needs <=2 H[b]*L[a] terms.
__global__ __launch_bounds__(256, 4) void lenet_circuit_kernel(
    const float* __restrict__ images,
    const float* __restrict__ c1b, const float* __restrict__ c2b,
    const float* __restrict__ f1b, const float* __restrict__ f2b,
    const float* __restrict__ f3b, const uint4* __restrict__ wsb,
    float* __restrict__ out)
{
    __shared__ __align__(16) unsigned char s_mem[39680];
    unsigned*       imgu = (unsigned*)s_mem;
    uint2*          imgw = (uint2*)s_mem;
    unsigned short* p1s  = (unsigned short*)(s_mem + 12672);
    const uint4*    p1u4 = (const uint4*)(s_mem + 12672);
    unsigned*       A1d  = (unsigned*)(s_mem + 31232);
    const uint4*    A1q  = (const uint4*)(s_mem + 31232);
    float*          pgf  = (float*)(s_mem + 7680);    // [16][12] probs
    float*          Hf   = (float*)(s_mem + 8448);    // [4][20]
    float*          Lf   = (float*)(s_mem + 8768);    // [4][20]

    const int t = threadIdx.x, bid = blockIdx.x;
    const int lane = t & 63, wav = t >> 6;   // 4 waves
    const int c = lane & 15, h = lane >> 4;
    const uint4 z4 = {0u, 0u, 0u, 0u};

    // conv1 column decomposition: c = (qxo<<2) | (parity<<1) | irel
    const int qxo = c >> 2, parity = (c >> 1) & 1, irel = c & 1;

    // ---- zero own p1 region (wave-private; pad ch 6-7 must stay 0) ----
    {
        uint4* pz = (uint4*)(s_mem + 12672) + 2 * wav * 145;
        for (int j = lane; j < 290; j += 64) pz[j] = z4;
    }
    // ---- load weight fragments (coalesced) ----
    Frag8 a1; a1.q = wsb[6336 + lane];
    Frag8 w2[7];
    #pragma unroll
    for (int s = 0; s < 7; ++s) w2[s].q = wsb[5824 + s * 64 + lane];
    int koff[7];
    #pragma unroll
    for (int s = 0; s < 7; ++s) {
        const int pos = 4 * s + h;
        koff[s] = (pos < 25) ? (pos / 5) * 12 + (pos % 5) : 0;
    }
    int pd[4];
    #pragma unroll
    for (int q = 0; q < 4; ++q) {
        const int p = 4 * h + q;
        pd[q] = (p < 15) ? (p / 3) * 14 + (p % 3) : 0;
    }
    float bias0 = 0.f, bias1 = 0.f;
    if (h < 3) { bias0 = c1b[2 * h]; bias1 = c1b[2 * h + 1]; }
    const float b2v = c2b[c];

    // ---- prefetch own pass-1 images into registers ----
    float4 pf[7];
    {
        const float4* g1 = (const float4*)(images + (size_t)bid * 12544 + 6272) + 392 * wav;
        #pragma unroll
        for (int k = 0; k < 7; ++k) {
            const int i = lane + 64 * k;
            if (i < 392) pf[k] = g1[i];
        }
    }

    // ---- wave-private conv phases ----
    auto do_stage1 = [&]() {   // write own pass-1 images from pf regs
        #pragma unroll
        for (int k = 0; k < 7; ++k) {
            const int i = lane + 64 * k;
            if (i < 392) {
                const int im = 2 * wav + (i >= 196);
                const int j = i - ((i >= 196) ? 196 : 0);
                uint2 wv; wv.x = pk_bf16(pf[k].x, pf[k].y); wv.y = pk_bf16(pf[k].z, pf[k].w);
                imgw[im * 198 + j] = wv;
            }
        }
    };
    auto do_conv1 = [&]() {
        const int img = 2 * wav + irel;
        const int imb = img * 396 + parity * 14 + qxo;
        for (int qy = 0; qy < 12; ++qy) {
            #pragma unroll
            for (int qxg = 0; qxg < 3; ++qxg) {
                const int base = imb + qy * 28 + qxg * 4;
                Frag8 bf;
                #pragma unroll
                for (int q = 0; q < 4; ++q) bf.u[q] = imgu[base + pd[q]];
                float4v acc = {0.f, 0.f, 0.f, 0.f};
                acc = __builtin_amdgcn_mfma_f32_16x16x32_bf16(a1.v, bf.v, acc, 0, 0, 0);
                float v0 = fmaxf(acc[0], acc[1]);   // ch 2h, xs-pooled
                float v1 = fmaxf(acc[2], acc[3]);   // ch 2h+1
                v0 = fmaxf(v0, __shfl_xor(v0, 2));  // y-parity pool: lane bit 1
                v1 = fmaxf(v1, __shfl_xor(v1, 2));
                if (parity == 0 && h < 3) {
                    const int qx = qxg * 4 + qxo;
                    *(unsigned*)&p1s[img * 1160 + qy * 96 + qx * 8 + 2 * h] =
                        pk_bf16(fmaxf(v0 + bias0, 0.f), fmaxf(v1 + bias1, 0.f));
                }
            }
        }
    };
    auto do_conv2 = [&](int pass) {
        const int pxl = (c & 1) + 2 * ((c >> 2) & 1);
        const int pyl = ((c >> 1) & 1) + 2 * ((c >> 3) & 1);
        #pragma unroll
        for (int ii = 0; ii < 2; ++ii) {
            const int i0 = 2 * wav + ii;
            #pragma unroll
            for (int mt = 0; mt < 4; ++mt) {
                const int px = pxl + 4 * (mt & 1), py = pyl + 4 * (mt >> 1);
                const int base = i0 * 145 + py * 12 + px;
                float4v acc = {0.f, 0.f, 0.f, 0.f};
                #pragma unroll
                for (int s = 0; s < 7; ++s) {
                    Frag8 af; af.q = p1u4[base + koff[s]];
                    acc = __builtin_amdgcn_mfma_f32_16x16x32_bf16(af.v, w2[s].v, acc, 0, 0, 0);
                }
                const float p = fmaxf(fmaxf(acc[0], acc[1]), fmaxf(acc[2], acc[3]));
                float v = fmaxf(p + b2v, 0.f);
                const float vp = __shfl_xor(v, 16);
                if ((h & 1) == 0) {
                    const int qy = (h >> 1) + 2 * (mt >> 1);
                    A1d[(pass * 8 + i0) * 132 + c * 8 + qy * 2 + (mt & 1)] = pk_bf16(v, vp);
                }
            }
        }
    };

    // ================= pass 0: stage own 2 images =================
    {
        const float4* g = (const float4*)(images + (size_t)bid * 12544) + 392 * wav;
        #pragma unroll
        for (int k = 0; k < 7; ++k) {
            const int i = lane + 64 * k;
            if (i < 392) {
                const float4 v = g[i];
                const int im = 2 * wav + (i >= 196);
                const int j = i - ((i >= 196) ? 196 : 0);
                uint2 wv; wv.x = pk_bf16(v.x, v.y); wv.y = pk_bf16(v.z, v.w);
                imgw[im * 198 + j] = wv;
            }
        }
    }
    do_conv1();          // own images; same-wave DS order after staging
    do_stage1();         // overwrite own imgu (conv1 reads already queued)
    do_conv2(0);
    do_conv1();
    do_conv2(1);

    // ---- prefetch fc1 B-frags (s=0..3, both n-tiles) BEFORE the barrier:
    // L2 latency hides under the barrier drain + other waves' conv tails ----
    const int nt0 = 2 * wav;
    Frag8 fB0[4], fB1[4];
    #pragma unroll
    for (int s = 0; s < 4; ++s) {
        fB0[s].q = wsb[(nt0 * 8 + s) * 64 + lane];
        fB1[s].q = wsb[((nt0 + 1) * 8 + s) * 64 + lane];
    }
    __syncthreads();     // A1 complete; imgu/p1 dead

    // ---- fc1 via MFMA (2 n-tiles/wave, 16 MFMA), batched B loads ----
    {
        unsigned* A2d = (unsigned*)s_mem;
        if (t < 64) A2d[(t >> 2) * 68 + 60 + (t & 3)] = 0u;   // k-pad 120-127
        // second-half batch issued up front: one wait, not four
        Frag8 gB0[4], gB1[4];
        #pragma unroll
        for (int s = 0; s < 4; ++s) {
            gB0[s].q = wsb[(nt0 * 8 + 4 + s) * 64 + lane];
            gB1[s].q = wsb[((nt0 + 1) * 8 + 4 + s) * 64 + lane];
        }
        float4v acc0 = {0.f, 0.f, 0.f, 0.f}, acc1 = acc0;
        #pragma unroll
        for (int s = 0; s < 4; ++s) {
            Frag8 af; af.q = A1q[c * 33 + 4 * s + h];
            acc0 = __builtin_amdgcn_mfma_f32_16x16x32_bf16(af.v, fB0[s].v, acc0, 0, 0, 0);
            acc1 = __builtin_amdgcn_mfma_f32_16x16x32_bf16(af.v, fB1[s].v, acc1, 0, 0, 0);
        }
        #pragma unroll
        for (int s = 0; s < 4; ++s) {
            Frag8 af; af.q = A1q[c * 33 + 4 * (4 + s) + h];
            acc0 = __builtin_amdgcn_mfma_f32_16x16x32_bf16(af.v, gB0[s].v, acc0, 0, 0, 0);
            acc1 = __builtin_amdgcn_mfma_f32_16x16x32_bf16(af.v, gB1[s].v, acc1, 0, 0, 0);
        }
        #pragma unroll
        for (int ntl = 0; ntl < 2; ++ntl) {
            const int o = 32 * wav + 16 * ntl + c;
            const float bias = (o < 120) ? f1b[o] : 0.f;
            #pragma unroll
            for (int r = 0; r < 4; ++r) {
                float v = fmaxf((ntl ? acc1[r] : acc0[r]) + bias, 0.f);
                const float vp = __shfl_xor(v, 1);
                if ((c & 1) == 0 && o < 120)
                    A2d[(4 * h + r) * 68 + (o >> 1)] = pk_bf16(v, vp);
            }
        }
    }
    // ---- prefetch fc2 B-frags (all 8) before the barrier ----
    Frag8 hB0[4], hB1[4];
    if (wav < 3) {
        #pragma unroll
        for (int s = 0; s < 4; ++s) {
            hB0[s].q = wsb[4096 + (nt0 * 4 + s) * 64 + lane];
            hB1[s].q = wsb[4096 + ((nt0 + 1) * 4 + s) * 64 + lane];
        }
    }
    __syncthreads();

    // ---- fc2 via MFMA (waves 0-2, 2 n-tiles each), prefetched B ----
    {
        unsigned* A3d = (unsigned*)(s_mem + 4352);
        if (t < 96) A3d[(t / 6) * 52 + 42 + (t % 6)] = 0u;    // k-pad 84-95
        if (wav < 3) {
            const uint4* A2q = (const uint4*)s_mem;
            float4v acc0 = {0.f, 0.f, 0.f, 0.f}, acc1 = acc0;
            #pragma unroll
            for (int s = 0; s < 4; ++s) {
                Frag8 af; af.q = A2q[c * 17 + 4 * s + h];
                acc0 = __builtin_amdgcn_mfma_f32_16x16x32_bf16(af.v, hB0[s].v, acc0, 0, 0, 0);
                acc1 = __builtin_amdgcn_mfma_f32_16x16x32_bf16(af.v, hB1[s].v, acc1, 0, 0, 0);
            }
            #pragma unroll
            for (int ntl = 0; ntl < 2; ++ntl) {
                const int o = 32 * wav + 16 * ntl + c;
                const float bias = (o < 84) ? f2b[o] : 0.f;
                #pragma unroll
                for (int r = 0; r < 4; ++r) {
                    float v = fmaxf((ntl ? acc1[r] : acc0[r]) + bias, 0.f);
                    const float vp = __shfl_xor(v, 1);
                    if ((c & 1) == 0 && o < 84)
                        A3d[(4 * h + r) * 52 + (o >> 1)] = pk_bf16(v, vp);
                }
            }
        }
    }
    // ---- prefetch fc3 B-frags (3) before the barrier ----
    Frag8 tB[3];
    #pragma unroll
    for (int s = 0; s < 3; ++s) tB[s].q = wsb[5632 + s * 64 + lane];
    __syncthreads();

    // ==== per-wave tail: fc3 + softmax + H/L + outputs for batch elem `wav`.
    // Every wave computes the full 16-row fc3 (redundant, 3 MFMA) but keeps
    // only its own rows (h == wav lanes). All LDS writes below are row-disjoint
    // across waves; intra-wave write->read ordering is by lgkmcnt. No barriers.
    {
        const uint4* A3q = (const uint4*)(s_mem + 4352);
        float4v acc = {0.f, 0.f, 0.f, 0.f};
        #pragma unroll
        for (int s = 0; s < 3; ++s) {
            Frag8 af; af.q = A3q[c * 13 + 4 * s + h];
            acc = __builtin_amdgcn_mfma_f32_16x16x32_bf16(af.v, tB[s].v, acc, 0, 0, 0);
        }
        const float bias = (c < 10) ? f3b[c] : 0.f;
        float x[4], m[4], e[4], sm[4];
        #pragma unroll
        for (int r = 0; r < 4; ++r) {
            x[r] = (c < 10) ? (acc[r] + bias) : -INFINITY;
            m[r] = x[r];
        }
        #pragma unroll
        for (int d = 1; d <= 8; d <<= 1)
            #pragma unroll
            for (int r = 0; r < 4; ++r) m[r] = fmaxf(m[r], __shfl_xor(m[r], d));
        #pragma unroll
        for (int r = 0; r < 4; ++r) { e[r] = (c < 10) ? expf(x[r] - m[r]) : 0.f; sm[r] = e[r]; }
        #pragma unroll
        for (int d = 1; d <= 8; d <<= 1)
            #pragma unroll
            for (int r = 0; r < 4; ++r) sm[r] += __shfl_xor(sm[r], d);
        if (c < 10 && h == wav) {
            #pragma unroll
            for (int r = 0; r < 4; ++r)
                pgf[(4 * wav + r) * 12 + c] = e[r] / sm[r];
        }

        // ---- digit-sum convolutions for be = wav ----
        if (lane < 38) {
            const int isH = (lane < 19), b = isH ? lane : lane - 19;
            const float* pg = pgf + 4 * wav * 12;
            const float* PA = pg + (isH ? 0 : 12);    // digit 0 / 1
            const float* PB = pg + (isH ? 24 : 36);   // digit 2 / 3
            const int ilo = (b > 9) ? b - 9 : 0;
            const int ihi = (b < 9) ? b : 9;
            float s = 0.f;
            for (int i = ilo; i <= ihi; ++i) s += PA[i] * PB[b - i];
            (isH ? Hf : Lf)[wav * 20 + b] = s;
        }

        // ---- outputs for be = wav: P_sum(s) = sum H[b]*L[s-10b] (<=2 terms) ----
        const float* H = Hf + wav * 20;
        const float* L = Lf + wav * 20;
        for (int s = lane; s < SUMS; s += 64) {
            const int bmin = (s > 18) ? (s - 9) / 10 : 0;
            int bmax = s / 10; if (bmax > 18) bmax = 18;
            float sum = 0.f;
            for (int b = bmin; b <= bmax; ++b) sum += H[b] * L[s - 10 * b];
            out[((size_t)bid * 4 + wav) * SUMS + s] = logf(sum);
        }
    }
}

extern "C" void kernel_launch(void* const* d_in, const int* in_sizes, int n_in,
                              void* d_out, int out_size, void* d_ws, size_t ws_size,
                              hipStream_t stream) {
    const float* images = (const float*)d_in[0];
    const float* c1w = (const float*)d_in[1];
    const float* c1b = (const float*)d_in[2];
    const float* c2w = (const float*)d_in[3];
    const float* c2b = (const float*)d_in[4];
    const float* f1w = (const float*)d_in[5];
    const float* f1b = (const float*)d_in[6];
    const float* f2w = (const float*)d_in[7];
    const float* f2b = (const float*)d_in[8];
    const float* f3w = (const float*)d_in[9];
    const float* f3b = (const float*)d_in[10];
    float* out = (float*)d_out;

    convert_weights<<<25, 256, 0, stream>>>(f1w, f2w, f3w, c1w, c2w, (uint4*)d_ws);
    lenet_circuit_kernel<<<NBLK, 256, 0, stream>>>(
        images, c1b, c2b, f1b, f2b, f3b, (const uint4*)d_ws, out);
}

// Round 7
// 133.455 us; speedup vs baseline: 1.0228x; 1.0228x over previous
//
#include <hip/hip_runtime.h>
#include <hip/hip_bf16.h>
#include <math.h>

#define SUMS 199
#define NBLK 1024   // 16 images = 4 batch elements per block, 256 threads

typedef __attribute__((ext_vector_type(8))) short short8;   // 8 bf16
typedef __attribute__((ext_vector_type(4))) float float4v;  // MFMA acc

union Frag8 { short8 v; unsigned u[4]; uint4 q; };

static __device__ inline unsigned pk_bf16(float a, float b) {
    __hip_bfloat162 h = __float22bfloat162_rn(make_float2(a, b));
    union { __hip_bfloat162 h; unsigned u; } c; c.h = h; return c.u;
}

// ---- pre-kernel: all weight fragments -> d_ws (bf16 frag layout) ----
// c2 K-map (dense): pos = 4*s + h, ky = pos/5, kx = pos%5, valid pos < 25
// => conv2 needs only 7 K-steps (K=224) instead of 8 (K=256).
__global__ __launch_bounds__(256) void convert_weights(
    const float* __restrict__ f1w, const float* __restrict__ f2w,
    const float* __restrict__ f3w, const float* __restrict__ c1w,
    const float* __restrict__ c2w, uint4* __restrict__ ws)
{
    const int g = blockIdx.x * 256 + threadIdx.x;
    if (g >= 6400) return;
    float v[8];
    if (g < 5824) {
        const float* W; int O, K, ld, nt, s, l;
        if (g < 4096)      { W = f1w; O = 120; K = 256; ld = 256; nt = g >> 9; s = (g >> 6) & 7; l = g & 63; }
        else if (g < 5632) { const int f = g - 4096; W = f2w; O = 84; K = 120; ld = 120; nt = f >> 8; s = (f >> 6) & 3; l = f & 63; }
        else               { const int f = g - 5632; W = f3w; O = 10; K = 84;  ld = 84;  nt = 0; s = f >> 6; l = f & 63; }
        const int o = nt * 16 + (l & 15);
        #pragma unroll
        for (int j = 0; j < 8; ++j) {
            const int k = 32 * s + 8 * (l >> 4) + j;
            v[j] = (o < O && k < K) ? W[o * ld + k] : 0.f;
        }
    } else if (g < 6336) {
        const int f = g - 5824, s = f >> 6, l = f & 63;
        const int c = l & 15, h = l >> 4;
        const int pos = 4 * s + h;           // dense position index
        const int ky = pos / 5, kx = pos % 5;
        const bool ok = (pos < 25);
        #pragma unroll
        for (int jp = 0; jp < 4; ++jp) {
            v[2 * jp]     = (ok && 2 * jp < 6)     ? c2w[c * 150 + (2 * jp) * 25 + ky * 5 + kx]     : 0.f;
            v[2 * jp + 1] = (ok && 2 * jp + 1 < 6) ? c2w[c * 150 + (2 * jp + 1) * 25 + ky * 5 + kx] : 0.f;
        }
    } else {
        const int l = (g - 6336) & 63;
        const int c = l & 15, h = l >> 4;
        const int oc = c >> 1, xs = c & 1;
        #pragma unroll
        for (int j = 0; j < 8; ++j) {
            const int p = h * 4 + (j >> 1);
            float w = 0.f;
            if (p < 15 && c < 12) {
                const int ky = p / 3, kx = 2 * (p % 3) + (j & 1) - xs;
                if (kx >= 0 && kx < 5) w = c1w[oc * 25 + ky * 5 + kx];
            }
            v[j] = w;
        }
    }
    uint4 r;
    r.x = pk_bf16(v[0], v[1]); r.y = pk_bf16(v[2], v[3]);
    r.z = pk_bf16(v[4], v[5]); r.w = pk_bf16(v[6], v[7]);
    ws[g] = r;
}

// LDS map (39680 B, 4 blocks/CU):
//  [0,12672)      imgu bf16 [8 img][396 dw] per pass. After convs: A2
//                 [16][68dw]@0, A3 [16][52dw]@4352, pgf [16][12]f32 @7680,
//                 Hf/Lf [4][20]f32 @8448/@8768.
//  [12672,31232)  p1 bf16 [8 img][145 uint4], ch-6/7 dwords stay zero.
//  [31232,39680)  A1 bf16 [16 img][132 dw]
//
// Wave-private front: wave w owns images {2w,2w+1} of each pass end-to-end
// (stage -> conv1 with N-cols (irel,parity,qxo) -> conv2); all hazards are
// same-wave DS program order; barriers only at A1->fc1, fc1->fc2, fc2->tail.
//
// R7: explicit ILP. Per-wave critical path was serialized load->use chains
// (VGPR_Count=56 showed the compiler never pipelined). conv1: batch the 12
// ds_reads per qy-row and double-buffer the next row's reads over the current
// row's MFMA+pool chains. conv2: batch the 7 b128 reads per mt-unit ahead of
// its MFMA chain; defer shfl+store epilogue of all 4 units (parallel chains).
// fc: batch A-frag LDS reads in groups ahead of the MFMA chains.
//
// Circuit factorization (exact regroup): n1+n2 = 10(h1+h2)+(l1+l2) =>
// P_sum = (ptens1 (*) ptens2) outer-convolved with (pones1 (*) pones2);
// H,L are 19-long convs; each of the 199 outputs needs <=2 H[b]*L[a] terms.
__global__ __launch_bounds__(256, 4) void lenet_circuit_kernel(
    const float* __restrict__ images,
    const float* __restrict__ c1b, const float* __restrict__ c2b,
    const float* __restrict__ f1b, const float* __restrict__ f2b,
    const float* __restrict__ f3b, const uint4* __restrict__ wsb,
    float* __restrict__ out)
{
    __shared__ __align__(16) unsigned char s_mem[39680];
    unsigned*       imgu = (unsigned*)s_mem;
    uint2*          imgw = (uint2*)s_mem;
    unsigned short* p1s  = (unsigned short*)(s_mem + 12672);
    const uint4*    p1u4 = (const uint4*)(s_mem + 12672);
    unsigned*       A1d  = (unsigned*)(s_mem + 31232);
    const uint4*    A1q  = (const uint4*)(s_mem + 31232);
    float*          pgf  = (float*)(s_mem + 7680);    // [16][12] probs
    float*          Hf   = (float*)(s_mem + 8448);    // [4][20]
    float*          Lf   = (float*)(s_mem + 8768);    // [4][20]

    const int t = threadIdx.x, bid = blockIdx.x;
    const int lane = t & 63, wav = t >> 6;   // 4 waves
    const int c = lane & 15, h = lane >> 4;
    const uint4 z4 = {0u, 0u, 0u, 0u};

    // conv1 column decomposition: c = (qxo<<2) | (parity<<1) | irel
    const int qxo = c >> 2, parity = (c >> 1) & 1, irel = c & 1;

    // ---- zero own p1 region (wave-private; pad ch 6-7 must stay 0) ----
    {
        uint4* pz = (uint4*)(s_mem + 12672) + 2 * wav * 145;
        for (int j = lane; j < 290; j += 64) pz[j] = z4;
    }
    // ---- load weight fragments (coalesced) ----
    Frag8 a1; a1.q = wsb[6336 + lane];
    Frag8 w2[7];
    #pragma unroll
    for (int s = 0; s < 7; ++s) w2[s].q = wsb[5824 + s * 64 + lane];
    int koff[7];
    #pragma unroll
    for (int s = 0; s < 7; ++s) {
        const int pos = 4 * s + h;
        koff[s] = (pos < 25) ? (pos / 5) * 12 + (pos % 5) : 0;
    }
    int pd[4];
    #pragma unroll
    for (int q = 0; q < 4; ++q) {
        const int p = 4 * h + q;
        pd[q] = (p < 15) ? (p / 3) * 14 + (p % 3) : 0;
    }
    float bias0 = 0.f, bias1 = 0.f;
    if (h < 3) { bias0 = c1b[2 * h]; bias1 = c1b[2 * h + 1]; }
    const float b2v = c2b[c];

    // ---- prefetch own pass-1 images into registers ----
    float4 pf[7];
    {
        const float4* g1 = (const float4*)(images + (size_t)bid * 12544 + 6272) + 392 * wav;
        #pragma unroll
        for (int k = 0; k < 7; ++k) {
            const int i = lane + 64 * k;
            if (i < 392) pf[k] = g1[i];
        }
    }

    // ---- wave-private conv phases ----
    auto do_stage1 = [&]() {   // write own pass-1 images from pf regs
        #pragma unroll
        for (int k = 0; k < 7; ++k) {
            const int i = lane + 64 * k;
            if (i < 392) {
                const int im = 2 * wav + (i >= 196);
                const int j = i - ((i >= 196) ? 196 : 0);
                uint2 wv; wv.x = pk_bf16(pf[k].x, pf[k].y); wv.y = pk_bf16(pf[k].z, pf[k].w);
                imgw[im * 198 + j] = wv;
            }
        }
    };
    // conv1: software-pipelined over qy. Batch 12 reads/row; next row's reads
    // issue before current row's MFMA+pool consume (double buffer dA/dB).
    auto do_conv1 = [&]() {
        const int img = 2 * wav + irel;
        const int imb = img * 396 + parity * 14 + qxo;
        const int pst = img * 1160 + 2 * h;   // p1 store base (ushort idx)
        unsigned dA[12], dB[12];
        #pragma unroll
        for (int x = 0; x < 3; ++x)
            #pragma unroll
            for (int q = 0; q < 4; ++q)
                dA[x * 4 + q] = imgu[imb + x * 4 + pd[q]];
        #pragma unroll
        for (int qy = 0; qy < 12; ++qy) {
            const unsigned* cur = (qy & 1) ? dB : dA;
            unsigned*       nxt = (qy & 1) ? dA : dB;
            if (qy < 11) {
                const int nb = imb + (qy + 1) * 28;
                #pragma unroll
                for (int x = 0; x < 3; ++x)
                    #pragma unroll
                    for (int q = 0; q < 4; ++q)
                        nxt[x * 4 + q] = imgu[nb + x * 4 + pd[q]];
            }
            float4v acc[3];
            #pragma unroll
            for (int x = 0; x < 3; ++x) {
                Frag8 bf;
                #pragma unroll
                for (int q = 0; q < 4; ++q) bf.u[q] = cur[x * 4 + q];
                float4v a0 = {0.f, 0.f, 0.f, 0.f};
                acc[x] = __builtin_amdgcn_mfma_f32_16x16x32_bf16(a1.v, bf.v, a0, 0, 0, 0);
            }
            float v0[3], v1[3];
            #pragma unroll
            for (int x = 0; x < 3; ++x) {
                v0[x] = fmaxf(acc[x][0], acc[x][1]);   // ch 2h, xs-pooled
                v1[x] = fmaxf(acc[x][2], acc[x][3]);   // ch 2h+1
            }
            #pragma unroll
            for (int x = 0; x < 3; ++x) {              // 6 parallel shfl chains
                v0[x] = fmaxf(v0[x], __shfl_xor(v0[x], 2));  // y-parity pool
                v1[x] = fmaxf(v1[x], __shfl_xor(v1[x], 2));
            }
            if (parity == 0 && h < 3) {
                #pragma unroll
                for (int x = 0; x < 3; ++x) {
                    const int qx = x * 4 + qxo;
                    *(unsigned*)&p1s[pst + qy * 96 + qx * 8] =
                        pk_bf16(fmaxf(v0[x] + bias0, 0.f), fmaxf(v1[x] + bias1, 0.f));
                }
            }
        }
    };
    // conv2: per mt-unit, batch the 7 b128 reads ahead of the 7-MFMA chain;
    // defer the shfl+store epilogue of all 4 units to run as parallel chains.
    auto do_conv2 = [&](int pass) {
        const int pxl = (c & 1) + 2 * ((c >> 2) & 1);
        const int pyl = ((c >> 1) & 1) + 2 * ((c >> 3) & 1);
        #pragma unroll
        for (int ii = 0; ii < 2; ++ii) {
            const int i0 = 2 * wav + ii;
            float ov[4];
            #pragma unroll
            for (int mt = 0; mt < 4; ++mt) {
                const int base = i0 * 145 + (pyl + 4 * (mt >> 1)) * 12 + pxl + 4 * (mt & 1);
                uint4 r[7];
                #pragma unroll
                for (int s = 0; s < 7; ++s) r[s] = p1u4[base + koff[s]];
                float4v acc = {0.f, 0.f, 0.f, 0.f};
                #pragma unroll
                for (int s = 0; s < 7; ++s) {
                    Frag8 af; af.q = r[s];
                    acc = __builtin_amdgcn_mfma_f32_16x16x32_bf16(af.v, w2[s].v, acc, 0, 0, 0);
                }
                const float p = fmaxf(fmaxf(acc[0], acc[1]), fmaxf(acc[2], acc[3]));
                ov[mt] = fmaxf(p + b2v, 0.f);
            }
            const int img = pass * 8 + i0;
            float vp[4];
            #pragma unroll
            for (int mt = 0; mt < 4; ++mt) vp[mt] = __shfl_xor(ov[mt], 16);
            if ((h & 1) == 0) {
                #pragma unroll
                for (int mt = 0; mt < 4; ++mt) {
                    const int qy = (h >> 1) + 2 * (mt >> 1);
                    A1d[img * 132 + c * 8 + qy * 2 + (mt & 1)] = pk_bf16(ov[mt], vp[mt]);
                }
            }
        }
    };

    // ================= pass 0: stage own 2 images =================
    {
        const float4* g = (const float4*)(images + (size_t)bid * 12544) + 392 * wav;
        #pragma unroll
        for (int k = 0; k < 7; ++k) {
            const int i = lane + 64 * k;
            if (i < 392) {
                const float4 v = g[i];
                const int im = 2 * wav + (i >= 196);
                const int j = i - ((i >= 196) ? 196 : 0);
                uint2 wv; wv.x = pk_bf16(v.x, v.y); wv.y = pk_bf16(v.z, v.w);
                imgw[im * 198 + j] = wv;
            }
        }
    }
    do_conv1();          // own images; same-wave DS order after staging
    do_stage1();         // overwrite own imgu (conv1 reads already queued)
    do_conv2(0);
    do_conv1();
    do_conv2(1);

    // ---- prefetch fc1 B-frags (s=0..3, both n-tiles) BEFORE the barrier ----
    const int nt0 = 2 * wav;
    Frag8 fB0[4], fB1[4];
    #pragma unroll
    for (int s = 0; s < 4; ++s) {
        fB0[s].q = wsb[(nt0 * 8 + s) * 64 + lane];
        fB1[s].q = wsb[((nt0 + 1) * 8 + s) * 64 + lane];
    }
    __syncthreads();     // A1 complete; imgu/p1 dead

    // ---- fc1 via MFMA (2 n-tiles/wave, 16 MFMA), batched A+B loads ----
    {
        unsigned* A2d = (unsigned*)s_mem;
        if (t < 64) A2d[(t >> 2) * 68 + 60 + (t & 3)] = 0u;   // k-pad 120-127
        // second-half B batch issued up front: one wait, not four
        Frag8 gB0[4], gB1[4];
        #pragma unroll
        for (int s = 0; s < 4; ++s) {
            gB0[s].q = wsb[(nt0 * 8 + 4 + s) * 64 + lane];
            gB1[s].q = wsb[((nt0 + 1) * 8 + 4 + s) * 64 + lane];
        }
        Frag8 afA[4];
        #pragma unroll
        for (int s = 0; s < 4; ++s) afA[s].q = A1q[c * 33 + 4 * s + h];
        float4v acc0 = {0.f, 0.f, 0.f, 0.f}, acc1 = acc0;
        #pragma unroll
        for (int s = 0; s < 4; ++s) {
            acc0 = __builtin_amdgcn_mfma_f32_16x16x32_bf16(afA[s].v, fB0[s].v, acc0, 0, 0, 0);
            acc1 = __builtin_amdgcn_mfma_f32_16x16x32_bf16(afA[s].v, fB1[s].v, acc1, 0, 0, 0);
        }
        #pragma unroll
        for (int s = 0; s < 4; ++s) afA[s].q = A1q[c * 33 + 4 * (4 + s) + h];
        #pragma unroll
        for (int s = 0; s < 4; ++s) {
            acc0 = __builtin_amdgcn_mfma_f32_16x16x32_bf16(afA[s].v, gB0[s].v, acc0, 0, 0, 0);
            acc1 = __builtin_amdgcn_mfma_f32_16x16x32_bf16(afA[s].v, gB1[s].v, acc1, 0, 0, 0);
        }
        #pragma unroll
        for (int ntl = 0; ntl < 2; ++ntl) {
            const int o = 32 * wav + 16 * ntl + c;
            const float bias = (o < 120) ? f1b[o] : 0.f;
            #pragma unroll
            for (int r = 0; r < 4; ++r) {
                float v = fmaxf((ntl ? acc1[r] : acc0[r]) + bias, 0.f);
                const float vp = __shfl_xor(v, 1);
                if ((c & 1) == 0 && o < 120)
                    A2d[(4 * h + r) * 68 + (o >> 1)] = pk_bf16(v, vp);
            }
        }
    }
    // ---- prefetch fc2 B-frags (all 8) before the barrier ----
    Frag8 hB0[4], hB1[4];
    if (wav < 3) {
        #pragma unroll
        for (int s = 0; s < 4; ++s) {
            hB0[s].q = wsb[4096 + (nt0 * 4 + s) * 64 + lane];
            hB1[s].q = wsb[4096 + ((nt0 + 1) * 4 + s) * 64 + lane];
        }
    }
    __syncthreads();

    // ---- fc2 via MFMA (waves 0-2, 2 n-tiles each), batched A, prefetched B ----
    {
        unsigned* A3d = (unsigned*)(s_mem + 4352);
        if (t < 96) A3d[(t / 6) * 52 + 42 + (t % 6)] = 0u;    // k-pad 84-95
        if (wav < 3) {
            const uint4* A2q = (const uint4*)s_mem;
            Frag8 afA[4];
            #pragma unroll
            for (int s = 0; s < 4; ++s) afA[s].q = A2q[c * 17 + 4 * s + h];
            float4v acc0 = {0.f, 0.f, 0.f, 0.f}, acc1 = acc0;
            #pragma unroll
            for (int s = 0; s < 4; ++s) {
                acc0 = __builtin_amdgcn_mfma_f32_16x16x32_bf16(afA[s].v, hB0[s].v, acc0, 0, 0, 0);
                acc1 = __builtin_amdgcn_mfma_f32_16x16x32_bf16(afA[s].v, hB1[s].v, acc1, 0, 0, 0);
            }
            #pragma unroll
            for (int ntl = 0; ntl < 2; ++ntl) {
                const int o = 32 * wav + 16 * ntl + c;
                const float bias = (o < 84) ? f2b[o] : 0.f;
                #pragma unroll
                for (int r = 0; r < 4; ++r) {
                    float v = fmaxf((ntl ? acc1[r] : acc0[r]) + bias, 0.f);
                    const float vp = __shfl_xor(v, 1);
                    if ((c & 1) == 0 && o < 84)
                        A3d[(4 * h + r) * 52 + (o >> 1)] = pk_bf16(v, vp);
                }
            }
        }
    }
    // ---- prefetch fc3 B-frags (3) before the barrier ----
    Frag8 tB[3];
    #pragma unroll
    for (int s = 0; s < 3; ++s) tB[s].q = wsb[5632 + s * 64 + lane];
    __syncthreads();

    // ==== per-wave tail: fc3 + softmax + H/L + outputs for batch elem `wav`.
    // Every wave computes the full 16-row fc3 (redundant, 3 MFMA) but keeps
    // only its own rows (h == wav lanes). All LDS writes below are row-disjoint
    // across waves; intra-wave write->read ordering is by lgkmcnt. No barriers.
    {
        const uint4* A3q = (const uint4*)(s_mem + 4352);
        Frag8 afA[3];
        #pragma unroll
        for (int s = 0; s < 3; ++s) afA[s].q = A3q[c * 13 + 4 * s + h];
        float4v acc = {0.f, 0.f, 0.f, 0.f};
        #pragma unroll
        for (int s = 0; s < 3; ++s)
            acc = __builtin_amdgcn_mfma_f32_16x16x32_bf16(afA[s].v, tB[s].v, acc, 0, 0, 0);
        const float bias = (c < 10) ? f3b[c] : 0.f;
        float x[4], m[4], e[4], sm[4];
        #pragma unroll
        for (int r = 0; r < 4; ++r) {
            x[r] = (c < 10) ? (acc[r] + bias) : -INFINITY;
            m[r] = x[r];
        }
        #pragma unroll
        for (int d = 1; d <= 8; d <<= 1)
            #pragma unroll
            for (int r = 0; r < 4; ++r) m[r] = fmaxf(m[r], __shfl_xor(m[r], d));
        #pragma unroll
        for (int r = 0; r < 4; ++r) { e[r] = (c < 10) ? expf(x[r] - m[r]) : 0.f; sm[r] = e[r]; }
        #pragma unroll
        for (int d = 1; d <= 8; d <<= 1)
            #pragma unroll
            for (int r = 0; r < 4; ++r) sm[r] += __shfl_xor(sm[r], d);
        if (c < 10 && h == wav) {
            #pragma unroll
            for (int r = 0; r < 4; ++r)
                pgf[(4 * wav + r) * 12 + c] = e[r] / sm[r];
        }

        // ---- digit-sum convolutions for be = wav ----
        if (lane < 38) {
            const int isH = (lane < 19), b = isH ? lane : lane - 19;
            const float* pg = pgf + 4 * wav * 12;
            const float* PA = pg + (isH ? 0 : 12);    // digit 0 / 1
            const float* PB = pg + (isH ? 24 : 36);   // digit 2 / 3
            const int ilo = (b > 9) ? b - 9 : 0;
            const int ihi = (b < 9) ? b : 9;
            float s = 0.f;
            for (int i = ilo; i <= ihi; ++i) s += PA[i] * PB[b - i];
            (isH ? Hf : Lf)[wav * 20 + b] = s;
        }

        // ---- outputs for be = wav: P_sum(s) = sum H[b]*L[s-10b] (<=2 terms) ----
        const float* H = Hf + wav * 20;
        const float* L = Lf + wav * 20;
        for (int s = lane; s < SUMS; s += 64) {
            const int bmin = (s > 18) ? (s - 9) / 10 : 0;
            int bmax = s / 10; if (bmax > 18) bmax = 18;
            float sum = 0.f;
            for (int b = bmin; b <= bmax; ++b) sum += H[b] * L[s - 10 * b];
            out[((size_t)bid * 4 + wav) * SUMS + s] = logf(sum);
        }
    }
}

extern "C" void kernel_launch(void* const* d_in, const int* in_sizes, int n_in,
                              void* d_out, int out_size, void* d_ws, size_t ws_size,
                              hipStream_t stream) {
    const float* images = (const float*)d_in[0];
    const float* c1w = (const float*)d_in[1];
    const float* c1b = (const float*)d_in[2];
    const float* c2w = (const float*)d_in[3];
    const float* c2b = (const float*)d_in[4];
    const float* f1w = (const float*)d_in[5];
    const float* f1b = (const float*)d_in[6];
    const float* f2w = (const float*)d_in[7];
    const float* f2b = (const float*)d_in[8];
    const float* f3w = (const float*)d_in[9];
    const float* f3b = (const float*)d_in[10];
    float* out = (float*)d_out;

    convert_weights<<<25, 256, 0, stream>>>(f1w, f2w, f3w, c1w, c2w, (uint4*)d_ws);
    lenet_circuit_kernel<<<NBLK, 256, 0, stream>>>(
        images, c1b, c2b, f1b, f2b, f3b, (const uint4*)d_ws, out);
}

// Round 8
// 128.161 us; speedup vs baseline: 1.0651x; 1.0413x over previous
//
#include <hip/hip_runtime.h>
#include <hip/hip_bf16.h>
#include <math.h>

#define SUMS 199
#define NBLK 1024   // 16 images = 4 batch elements per block, 256 threads

typedef __attribute__((ext_vector_type(8))) short short8;   // 8 bf16
typedef __attribute__((ext_vector_type(4))) float float4v;  // MFMA acc

union Frag8 { short8 v; unsigned u[4]; uint4 q; };

static __device__ inline unsigned pk_bf16(float a, float b) {
    __hip_bfloat162 h = __float22bfloat162_rn(make_float2(a, b));
    union { __hip_bfloat162 h; unsigned u; } c; c.h = h; return c.u;
}
static __device__ inline unsigned short bf16_1(float a) {
    union { __hip_bfloat16 h; unsigned short u; } c;
    c.h = __float2bfloat16(a); return c.u;
}
// Cross-lane via DPP quad_perm (pure VALU; __shfl_xor would be ds_bpermute
// on the LDS pipe, ~30-40cy dependent latency). 0x4E = xor-2, 0xB1 = xor-1.
template <int CTRL>
static __device__ inline float fmax_xdpp(float v) {
    const int s = __builtin_amdgcn_update_dpp(0, __float_as_int(v), CTRL, 0xF, 0xF, true);
    return fmaxf(v, __int_as_float(s));
}
template <int CTRL>
static __device__ inline float add_xdpp(float v) {
    const int s = __builtin_amdgcn_update_dpp(0, __float_as_int(v), CTRL, 0xF, 0xF, true);
    return v + __int_as_float(s);
}

// ---- pre-kernel: all weight fragments -> d_ws (bf16 frag layout) ----
// c2 K-map (dense): pos = 4*s + h, ky = pos/5, kx = pos%5, valid pos < 25
// => conv2 needs only 7 K-steps (K=224) instead of 8 (K=256).
__global__ __launch_bounds__(256) void convert_weights(
    const float* __restrict__ f1w, const float* __restrict__ f2w,
    const float* __restrict__ f3w, const float* __restrict__ c1w,
    const float* __restrict__ c2w, uint4* __restrict__ ws)
{
    const int g = blockIdx.x * 256 + threadIdx.x;
    if (g >= 6400) return;
    float v[8];
    if (g < 5824) {
        const float* W; int O, K, ld, nt, s, l;
        if (g < 4096)      { W = f1w; O = 120; K = 256; ld = 256; nt = g >> 9; s = (g >> 6) & 7; l = g & 63; }
        else if (g < 5632) { const int f = g - 4096; W = f2w; O = 84; K = 120; ld = 120; nt = f >> 8; s = (f >> 6) & 3; l = f & 63; }
        else               { const int f = g - 5632; W = f3w; O = 10; K = 84;  ld = 84;  nt = 0; s = f >> 6; l = f & 63; }
        const int o = nt * 16 + (l & 15);
        #pragma unroll
        for (int j = 0; j < 8; ++j) {
            const int k = 32 * s + 8 * (l >> 4) + j;
            v[j] = (o < O && k < K) ? W[o * ld + k] : 0.f;
        }
    } else if (g < 6336) {
        const int f = g - 5824, s = f >> 6, l = f & 63;
        const int c = l & 15, h = l >> 4;
        const int pos = 4 * s + h;           // dense position index
        const int ky = pos / 5, kx = pos % 5;
        const bool ok = (pos < 25);
        #pragma unroll
        for (int jp = 0; jp < 4; ++jp) {
            v[2 * jp]     = (ok && 2 * jp < 6)     ? c2w[c * 150 + (2 * jp) * 25 + ky * 5 + kx]     : 0.f;
            v[2 * jp + 1] = (ok && 2 * jp + 1 < 6) ? c2w[c * 150 + (2 * jp + 1) * 25 + ky * 5 + kx] : 0.f;
        }
    } else {
        const int l = (g - 6336) & 63;
        const int c = l & 15, h = l >> 4;
        const int oc = c >> 1, xs = c & 1;
        #pragma unroll
        for (int j = 0; j < 8; ++j) {
            const int p = h * 4 + (j >> 1);
            float w = 0.f;
            if (p < 15 && c < 12) {
                const int ky = p / 3, kx = 2 * (p % 3) + (j & 1) - xs;
                if (kx >= 0 && kx < 5) w = c1w[oc * 25 + ky * 5 + kx];
            }
            v[j] = w;
        }
    }
    uint4 r;
    r.x = pk_bf16(v[0], v[1]); r.y = pk_bf16(v[2], v[3]);
    r.z = pk_bf16(v[4], v[5]); r.w = pk_bf16(v[6], v[7]);
    ws[g] = r;
}

// LDS map (39680 B, 4 blocks/CU):
//  [0,12672)      imgu bf16 [8 img][396 dw] per pass. After convs: A2
//                 [16][68dw]@0, A3 [16][52dw]@4352, pgf [16][12]f32 @7680,
//                 Hf/Lf [4][20]f32 @8448/@8768.
//  [12672,31232)  p1 bf16 [8 img][145 uint4], ch-6/7 dwords stay zero.
//  [31232,39680)  A1 bf16 [16 img][132 dw]
//
// Wave-private front: wave w owns images {2w,2w+1} of each pass end-to-end
// (stage -> conv1 with N-cols (irel,parity,qxo) -> conv2); all hazards are
// same-wave DS program order; barriers only at A1->fc1, fc1->fc2, fc2->tail.
//
// R8: no cross-lane DS ops on hot chains. __shfl_xor = ds_bpermute (LDS
// pipe, ~30-40cy). conv1 pool -> DPP quad_perm; conv2/fc1/fc2 epilogues ->
// per-lane ds_write_b16 at the byte-identical packed address (no shfl, no
// pack, all 64 lanes store their own bf16). ~176 bpermutes/wave removed.
//
// Circuit factorization (exact regroup): n1+n2 = 10(h1+h2)+(l1+l2) =>
// P_sum = (ptens1 (*) ptens2) outer-convolved with (pones1 (*) pones2);
// H,L are 19-long convs; each of the 199 outputs needs <=2 H[b]*L[a] terms.
__global__ __launch_bounds__(256, 4) void lenet_circuit_kernel(
    const float* __restrict__ images,
    const float* __restrict__ c1b, const float* __restrict__ c2b,
    const float* __restrict__ f1b, const float* __restrict__ f2b,
    const float* __restrict__ f3b, const uint4* __restrict__ wsb,
    float* __restrict__ out)
{
    __shared__ __align__(16) unsigned char s_mem[39680];
    unsigned*       imgu = (unsigned*)s_mem;
    uint2*          imgw = (uint2*)s_mem;
    unsigned short* p1s  = (unsigned short*)(s_mem + 12672);
    const uint4*    p1u4 = (const uint4*)(s_mem + 12672);
    unsigned short* A1s  = (unsigned short*)(s_mem + 31232);
    const uint4*    A1q  = (const uint4*)(s_mem + 31232);
    float*          pgf  = (float*)(s_mem + 7680);    // [16][12] probs
    float*          Hf   = (float*)(s_mem + 8448);    // [4][20]
    float*          Lf   = (float*)(s_mem + 8768);    // [4][20]

    const int t = threadIdx.x, bid = blockIdx.x;
    const int lane = t & 63, wav = t >> 6;   // 4 waves
    const int c = lane & 15, h = lane >> 4;
    const uint4 z4 = {0u, 0u, 0u, 0u};

    // conv1 column decomposition: c = (qxo<<2) | (parity<<1) | irel
    const int qxo = c >> 2, parity = (c >> 1) & 1, irel = c & 1;

    // ---- zero own p1 region (wave-private; pad ch 6-7 must stay 0) ----
    {
        uint4* pz = (uint4*)(s_mem + 12672) + 2 * wav * 145;
        for (int j = lane; j < 290; j += 64) pz[j] = z4;
    }
    // ---- load weight fragments (coalesced) ----
    Frag8 a1; a1.q = wsb[6336 + lane];
    Frag8 w2[7];
    #pragma unroll
    for (int s = 0; s < 7; ++s) w2[s].q = wsb[5824 + s * 64 + lane];
    int koff[7];
    #pragma unroll
    for (int s = 0; s < 7; ++s) {
        const int pos = 4 * s + h;
        koff[s] = (pos < 25) ? (pos / 5) * 12 + (pos % 5) : 0;
    }
    int pd[4];
    #pragma unroll
    for (int q = 0; q < 4; ++q) {
        const int p = 4 * h + q;
        pd[q] = (p < 15) ? (p / 3) * 14 + (p % 3) : 0;
    }
    float bias0 = 0.f, bias1 = 0.f;
    if (h < 3) { bias0 = c1b[2 * h]; bias1 = c1b[2 * h + 1]; }
    const float b2v = c2b[c];

    // ---- prefetch own pass-1 images into registers ----
    float4 pf[7];
    {
        const float4* g1 = (const float4*)(images + (size_t)bid * 12544 + 6272) + 392 * wav;
        #pragma unroll
        for (int k = 0; k < 7; ++k) {
            const int i = lane + 64 * k;
            if (i < 392) pf[k] = g1[i];
        }
    }

    // ---- wave-private conv phases ----
    auto do_stage1 = [&]() {   // write own pass-1 images from pf regs
        #pragma unroll
        for (int k = 0; k < 7; ++k) {
            const int i = lane + 64 * k;
            if (i < 392) {
                const int im = 2 * wav + (i >= 196);
                const int j = i - ((i >= 196) ? 196 : 0);
                uint2 wv; wv.x = pk_bf16(pf[k].x, pf[k].y); wv.y = pk_bf16(pf[k].z, pf[k].w);
                imgw[im * 198 + j] = wv;
            }
        }
    };
    // conv1: software-pipelined over qy; pool via DPP (VALU only).
    auto do_conv1 = [&]() {
        const int img = 2 * wav + irel;
        const int imb = img * 396 + parity * 14 + qxo;
        const int pst = img * 1160 + 2 * h;   // p1 store base (ushort idx)
        unsigned dA[12], dB[12];
        #pragma unroll
        for (int x = 0; x < 3; ++x)
            #pragma unroll
            for (int q = 0; q < 4; ++q)
                dA[x * 4 + q] = imgu[imb + x * 4 + pd[q]];
        #pragma unroll
        for (int qy = 0; qy < 12; ++qy) {
            const unsigned* cur = (qy & 1) ? dB : dA;
            unsigned*       nxt = (qy & 1) ? dA : dB;
            if (qy < 11) {
                const int nb = imb + (qy + 1) * 28;
                #pragma unroll
                for (int x = 0; x < 3; ++x)
                    #pragma unroll
                    for (int q = 0; q < 4; ++q)
                        nxt[x * 4 + q] = imgu[nb + x * 4 + pd[q]];
            }
            float4v acc[3];
            #pragma unroll
            for (int x = 0; x < 3; ++x) {
                Frag8 bf;
                #pragma unroll
                for (int q = 0; q < 4; ++q) bf.u[q] = cur[x * 4 + q];
                float4v a0 = {0.f, 0.f, 0.f, 0.f};
                acc[x] = __builtin_amdgcn_mfma_f32_16x16x32_bf16(a1.v, bf.v, a0, 0, 0, 0);
            }
            float v0[3], v1[3];
            #pragma unroll
            for (int x = 0; x < 3; ++x) {
                v0[x] = fmax_xdpp<0x4E>(fmaxf(acc[x][0], acc[x][1]));  // xs + y-parity pool
                v1[x] = fmax_xdpp<0x4E>(fmaxf(acc[x][2], acc[x][3]));
            }
            if (parity == 0 && h < 3) {
                #pragma unroll
                for (int x = 0; x < 3; ++x) {
                    const int qx = x * 4 + qxo;
                    *(unsigned*)&p1s[pst + qy * 96 + qx * 8] =
                        pk_bf16(fmaxf(v0[x] + bias0, 0.f), fmaxf(v1[x] + bias1, 0.f));
                }
            }
        }
    };
    // conv2: batch 7 b128 reads per mt-unit; epilogue = per-lane b16 store
    // (ushort idx = 2*dword + (h&1); byte-identical to the old pk layout).
    auto do_conv2 = [&](int pass) {
        const int pxl = (c & 1) + 2 * ((c >> 2) & 1);
        const int pyl = ((c >> 1) & 1) + 2 * ((c >> 3) & 1);
        #pragma unroll
        for (int ii = 0; ii < 2; ++ii) {
            const int i0 = 2 * wav + ii;
            float ov[4];
            #pragma unroll
            for (int mt = 0; mt < 4; ++mt) {
                const int base = i0 * 145 + (pyl + 4 * (mt >> 1)) * 12 + pxl + 4 * (mt & 1);
                uint4 r[7];
                #pragma unroll
                for (int s = 0; s < 7; ++s) r[s] = p1u4[base + koff[s]];
                float4v acc = {0.f, 0.f, 0.f, 0.f};
                #pragma unroll
                for (int s = 0; s < 7; ++s) {
                    Frag8 af; af.q = r[s];
                    acc = __builtin_amdgcn_mfma_f32_16x16x32_bf16(af.v, w2[s].v, acc, 0, 0, 0);
                }
                const float p = fmaxf(fmaxf(acc[0], acc[1]), fmaxf(acc[2], acc[3]));
                ov[mt] = fmaxf(p + b2v, 0.f);
            }
            const int img = pass * 8 + i0;
            #pragma unroll
            for (int mt = 0; mt < 4; ++mt) {
                const int qy = (h >> 1) + 2 * (mt >> 1);
                A1s[img * 264 + c * 16 + qy * 4 + 2 * (mt & 1) + (h & 1)] = bf16_1(ov[mt]);
            }
        }
    };

    // ================= pass 0: stage own 2 images =================
    {
        const float4* g = (const float4*)(images + (size_t)bid * 12544) + 392 * wav;
        #pragma unroll
        for (int k = 0; k < 7; ++k) {
            const int i = lane + 64 * k;
            if (i < 392) {
                const float4 v = g[i];
                const int im = 2 * wav + (i >= 196);
                const int j = i - ((i >= 196) ? 196 : 0);
                uint2 wv; wv.x = pk_bf16(v.x, v.y); wv.y = pk_bf16(v.z, v.w);
                imgw[im * 198 + j] = wv;
            }
        }
    }
    do_conv1();          // own images; same-wave DS order after staging
    do_stage1();         // overwrite own imgu (conv1 reads already queued)
    do_conv2(0);
    do_conv1();
    do_conv2(1);

    // ---- prefetch fc1 B-frags (s=0..3, both n-tiles) BEFORE the barrier ----
    const int nt0 = 2 * wav;
    Frag8 fB0[4], fB1[4];
    #pragma unroll
    for (int s = 0; s < 4; ++s) {
        fB0[s].q = wsb[(nt0 * 8 + s) * 64 + lane];
        fB1[s].q = wsb[((nt0 + 1) * 8 + s) * 64 + lane];
    }
    __syncthreads();     // A1 complete; imgu/p1 dead

    // ---- fc1 via MFMA (2 n-tiles/wave, 16 MFMA), batched A+B loads ----
    {
        unsigned* A2d = (unsigned*)s_mem;
        unsigned short* A2s = (unsigned short*)s_mem;
        if (t < 64) A2d[(t >> 2) * 68 + 60 + (t & 3)] = 0u;   // k-pad 120-127
        // second-half B batch issued up front: one wait, not four
        Frag8 gB0[4], gB1[4];
        #pragma unroll
        for (int s = 0; s < 4; ++s) {
            gB0[s].q = wsb[(nt0 * 8 + 4 + s) * 64 + lane];
            gB1[s].q = wsb[((nt0 + 1) * 8 + 4 + s) * 64 + lane];
        }
        Frag8 afA[4];
        #pragma unroll
        for (int s = 0; s < 4; ++s) afA[s].q = A1q[c * 33 + 4 * s + h];
        float4v acc0 = {0.f, 0.f, 0.f, 0.f}, acc1 = acc0;
        #pragma unroll
        for (int s = 0; s < 4; ++s) {
            acc0 = __builtin_amdgcn_mfma_f32_16x16x32_bf16(afA[s].v, fB0[s].v, acc0, 0, 0, 0);
            acc1 = __builtin_amdgcn_mfma_f32_16x16x32_bf16(afA[s].v, fB1[s].v, acc1, 0, 0, 0);
        }
        #pragma unroll
        for (int s = 0; s < 4; ++s) afA[s].q = A1q[c * 33 + 4 * (4 + s) + h];
        #pragma unroll
        for (int s = 0; s < 4; ++s) {
            acc0 = __builtin_amdgcn_mfma_f32_16x16x32_bf16(afA[s].v, gB0[s].v, acc0, 0, 0, 0);
            acc1 = __builtin_amdgcn_mfma_f32_16x16x32_bf16(afA[s].v, gB1[s].v, acc1, 0, 0, 0);
        }
        #pragma unroll
        for (int ntl = 0; ntl < 2; ++ntl) {
            const int o = 32 * wav + 16 * ntl + c;
            if (o < 120) {
                const float bias = f1b[o];
                #pragma unroll
                for (int r = 0; r < 4; ++r) {
                    const float v = fmaxf((ntl ? acc1[r] : acc0[r]) + bias, 0.f);
                    A2s[(4 * h + r) * 136 + o] = bf16_1(v);   // per-lane b16 store
                }
            }
        }
    }
    // ---- prefetch fc2 B-frags (all 8) before the barrier ----
    Frag8 hB0[4], hB1[4];
    if (wav < 3) {
        #pragma unroll
        for (int s = 0; s < 4; ++s) {
            hB0[s].q = wsb[4096 + (nt0 * 4 + s) * 64 + lane];
            hB1[s].q = wsb[4096 + ((nt0 + 1) * 4 + s) * 64 + lane];
        }
    }
    __syncthreads();

    // ---- fc2 via MFMA (waves 0-2, 2 n-tiles each), batched A, prefetched B ----
    {
        unsigned* A3d = (unsigned*)(s_mem + 4352);
        unsigned short* A3s = (unsigned short*)(s_mem + 4352);
        if (t < 96) A3d[(t / 6) * 52 + 42 + (t % 6)] = 0u;    // k-pad 84-95
        if (wav < 3) {
            const uint4* A2q = (const uint4*)s_mem;
            Frag8 afA[4];
            #pragma unroll
            for (int s = 0; s < 4; ++s) afA[s].q = A2q[c * 17 + 4 * s + h];
            float4v acc0 = {0.f, 0.f, 0.f, 0.f}, acc1 = acc0;
            #pragma unroll
            for (int s = 0; s < 4; ++s) {
                acc0 = __builtin_amdgcn_mfma_f32_16x16x32_bf16(afA[s].v, hB0[s].v, acc0, 0, 0, 0);
                acc1 = __builtin_amdgcn_mfma_f32_16x16x32_bf16(afA[s].v, hB1[s].v, acc1, 0, 0, 0);
            }
            #pragma unroll
            for (int ntl = 0; ntl < 2; ++ntl) {
                const int o = 32 * wav + 16 * ntl + c;
                if (o < 84) {
                    const float bias = f2b[o];
                    #pragma unroll
                    for (int r = 0; r < 4; ++r) {
                        const float v = fmaxf((ntl ? acc1[r] : acc0[r]) + bias, 0.f);
                        A3s[(4 * h + r) * 104 + o] = bf16_1(v);   // per-lane b16 store
                    }
                }
            }
        }
    }
    // ---- prefetch fc3 B-frags (3) before the barrier ----
    Frag8 tB[3];
    #pragma unroll
    for (int s = 0; s < 3; ++s) tB[s].q = wsb[5632 + s * 64 + lane];
    __syncthreads();

    // ==== per-wave tail: fc3 + softmax + H/L + outputs for batch elem `wav`.
    // Every wave computes the full 16-row fc3 (redundant, 3 MFMA) but keeps
    // only its own rows (h == wav lanes). All LDS writes below are row-disjoint
    // across waves; intra-wave write->read ordering is by lgkmcnt. No barriers.
    {
        const uint4* A3q = (const uint4*)(s_mem + 4352);
        Frag8 afA[3];
        #pragma unroll
        for (int s = 0; s < 3; ++s) afA[s].q = A3q[c * 13 + 4 * s + h];
        float4v acc = {0.f, 0.f, 0.f, 0.f};
        #pragma unroll
        for (int s = 0; s < 3; ++s)
            acc = __builtin_amdgcn_mfma_f32_16x16x32_bf16(afA[s].v, tB[s].v, acc, 0, 0, 0);
        const float bias = (c < 10) ? f3b[c] : 0.f;
        float x[4], m[4], e[4], sm[4];
        #pragma unroll
        for (int r = 0; r < 4; ++r) {
            x[r] = (c < 10) ? (acc[r] + bias) : -INFINITY;
            m[r] = x[r];
        }
        #pragma unroll
        for (int r = 0; r < 4; ++r) m[r] = fmax_xdpp<0xB1>(m[r]);   // xor 1 (DPP)
        #pragma unroll
        for (int r = 0; r < 4; ++r) m[r] = fmax_xdpp<0x4E>(m[r]);   // xor 2 (DPP)
        #pragma unroll
        for (int d = 4; d <= 8; d <<= 1)
            #pragma unroll
            for (int r = 0; r < 4; ++r) m[r] = fmaxf(m[r], __shfl_xor(m[r], d));
        #pragma unroll
        for (int r = 0; r < 4; ++r) { e[r] = (c < 10) ? expf(x[r] - m[r]) : 0.f; sm[r] = e[r]; }
        #pragma unroll
        for (int r = 0; r < 4; ++r) sm[r] = add_xdpp<0xB1>(sm[r]);  // xor 1 (DPP)
        #pragma unroll
        for (int r = 0; r < 4; ++r) sm[r] = add_xdpp<0x4E>(sm[r]);  // xor 2 (DPP)
        #pragma unroll
        for (int d = 4; d <= 8; d <<= 1)
            #pragma unroll
            for (int r = 0; r < 4; ++r) sm[r] += __shfl_xor(sm[r], d);
        if (c < 10 && h == wav) {
            #pragma unroll
            for (int r = 0; r < 4; ++r)
                pgf[(4 * wav + r) * 12 + c] = e[r] / sm[r];
        }

        // ---- digit-sum convolutions for be = wav ----
        if (lane < 38) {
            const int isH = (lane < 19), b = isH ? lane : lane - 19;
            const float* pg = pgf + 4 * wav * 12;
            const float* PA = pg + (isH ? 0 : 12);    // digit 0 / 1
            const float* PB = pg + (isH ? 24 : 36);   // digit 2 / 3
            const int ilo = (b > 9) ? b - 9 : 0;
            const int ihi = (b < 9) ? b : 9;
            float s = 0.f;
            for (int i = ilo; i <= ihi; ++i) s += PA[i] * PB[b - i];
            (isH ? Hf : Lf)[wav * 20 + b] = s;
        }

        // ---- outputs for be = wav: P_sum(s) = sum H[b]*L[s-10b] (<=2 terms) ----
        const float* H = Hf + wav * 20;
        const float* L = Lf + wav * 20;
        for (int s = lane; s < SUMS; s += 64) {
            const int bmin = (s > 18) ? (s - 9) / 10 : 0;
            int bmax = s / 10; if (bmax > 18) bmax = 18;
            float sum = 0.f;
            for (int b = bmin; b <= bmax; ++b) sum += H[b] * L[s - 10 * b];
            out[((size_t)bid * 4 + wav) * SUMS + s] = logf(sum);
        }
    }
}

extern "C" void kernel_launch(void* const* d_in, const int* in_sizes, int n_in,
                              void* d_out, int out_size, void* d_ws, size_t ws_size,
                              hipStream_t stream) {
    const float* images = (const float*)d_in[0];
    const float* c1w = (const float*)d_in[1];
    const float* c1b = (const float*)d_in[2];
    const float* c2w = (const float*)d_in[3];
    const float* c2b = (const float*)d_in[4];
    const float* f1w = (const float*)d_in[5];
    const float* f1b = (const float*)d_in[6];
    const float* f2w = (const float*)d_in[7];
    const float* f2b = (const float*)d_in[8];
    const float* f3w = (const float*)d_in[9];
    const float* f3b = (const float*)d_in[10];
    float* out = (float*)d_out;

    convert_weights<<<25, 256, 0, stream>>>(f1w, f2w, f3w, c1w, c2w, (uint4*)d_ws);
    lenet_circuit_kernel<<<NBLK, 256, 0, stream>>>(
        images, c1b, c2b, f1b, f2b, f3b, (const uint4*)d_ws, out);
}